// Round 6
// baseline (259.340 us; speedup 1.0000x reference)
//
#include <hip/hip_runtime.h>

#define TT 200
#define FF 32
#define HH 50
#define PITCH 68   // u32 pitch of h LDS rows

typedef __attribute__((ext_vector_type(8))) short short8;   // 8 bf16 = 4 VGPR
typedef __attribute__((ext_vector_type(4))) float f32x4;
typedef __attribute__((ext_vector_type(4))) unsigned int uint32x4;

__device__ __forceinline__ unsigned short f2bf_rne(float f) {
    unsigned u = __float_as_uint(f);
    unsigned r = u + 0x7fffu + ((u >> 16) & 1u);
    return (unsigned short)(r >> 16);
}
__device__ __forceinline__ float fast_tanh(float x) {
    float e = __expf(2.0f * x);
    return 1.0f - __fdividef(2.0f, e + 1.0f);
}
__device__ __forceinline__ float trunc_hi(float v) {
    return __uint_as_float(__float_as_uint(v) & 0xffff0000u);
}
__device__ __forceinline__ f32x4 mfma16(short8 a, short8 b, f32x4 c) {
    return __builtin_amdgcn_mfma_f32_16x16x32_bf16(a, b, c, 0, 0, 0);
}

// Split fp32 column-slice of M[kdim x 50] into bf16 hi/lo B-frags.
// Layout (validated r4): lane(r,g) elem e -> B[k=kbase+8g+e][col=c].
__device__ __forceinline__ void build_bfrag(const float* __restrict__ M, int kbase,
                                            int kmax, int c, bool cv, int g,
                                            short8& hi, short8& lo) {
    unsigned ph[4], pl[4];
#pragma unroll
    for (int p = 0; p < 4; ++p) {
        const int k0 = kbase + 8 * g + 2 * p, k1 = k0 + 1;
        float v0 = (cv && k0 < kmax) ? M[k0 * HH + c] : 0.0f;
        float v1 = (cv && k1 < kmax) ? M[k1 * HH + c] : 0.0f;
        unsigned short h0 = f2bf_rne(v0), h1 = f2bf_rne(v1);
        ph[p] = ((unsigned)h1 << 16) | h0;
        float r0 = v0 - __uint_as_float((unsigned)h0 << 16);
        float r1 = v1 - __uint_as_float((unsigned)h1 << 16);
        unsigned short l0 = f2bf_rne(r0), l1 = f2bf_rne(r1);
        pl[p] = ((unsigned)l1 << 16) | l0;
    }
    uint32x4 h4 = {ph[0], ph[1], ph[2], ph[3]};
    uint32x4 l4 = {pl[0], pl[1], pl[2], pl[3]};
    hi = __builtin_bit_cast(short8, h4);
    lo = __builtin_bit_cast(short8, l4);
}

// Truncation-split 8 fp32 -> bf16 hi/lo A-frags.
__device__ __forceinline__ void split8(float4 a, float4 b, short8& hi, short8& lo) {
    float v[8] = {a.x, a.y, a.z, a.w, b.x, b.y, b.z, b.w};
    unsigned ph[4], pl[4];
#pragma unroll
    for (int p = 0; p < 4; ++p) {
        unsigned u0 = __float_as_uint(v[2 * p]);
        unsigned u1 = __float_as_uint(v[2 * p + 1]);
        ph[p] = __builtin_amdgcn_perm(u1, u0, 0x07060302u);
        float r0 = v[2 * p]     - __uint_as_float(u0 & 0xffff0000u);
        float r1 = v[2 * p + 1] - __uint_as_float(u1 & 0xffff0000u);
        pl[p] = __builtin_amdgcn_perm(__float_as_uint(r1), __float_as_uint(r0), 0x07060302u);
    }
    uint32x4 h4 = {ph[0], ph[1], ph[2], ph[3]};
    uint32x4 l4 = {pl[0], pl[1], pl[2], pl[3]};
    hi = __builtin_bit_cast(short8, h4);
    lo = __builtin_bit_cast(short8, l4);
}

// Unpack 8 LDS-packed h words (lo16=hh, hi16=hl residual) into A-frags.
__device__ __forceinline__ void unpack8(uint32x4 p0, uint32x4 p1, short8& hh, short8& hl) {
    unsigned ph[4], pl[4];
    ph[0] = __builtin_amdgcn_perm(p0[1], p0[0], 0x05040100u);
    ph[1] = __builtin_amdgcn_perm(p0[3], p0[2], 0x05040100u);
    ph[2] = __builtin_amdgcn_perm(p1[1], p1[0], 0x05040100u);
    ph[3] = __builtin_amdgcn_perm(p1[3], p1[2], 0x05040100u);
    pl[0] = __builtin_amdgcn_perm(p0[1], p0[0], 0x07060302u);
    pl[1] = __builtin_amdgcn_perm(p0[3], p0[2], 0x07060302u);
    pl[2] = __builtin_amdgcn_perm(p1[1], p1[0], 0x07060302u);
    pl[3] = __builtin_amdgcn_perm(p1[3], p1[2], 0x07060302u);
    uint32x4 h4 = {ph[0], ph[1], ph[2], ph[3]};
    uint32x4 l4 = {pl[0], pl[1], pl[2], pl[3]};
    hh = __builtin_bit_cast(short8, h4);
    hl = __builtin_bit_cast(short8, l4);
}

// Block = 32 rows = TWO independent 16-row groups (A,B), 2 waves.
// Wave w owns cols 32w..32w+31 for BOTH groups; W/U frags shared.
// The two recurrence chains are independent -> each fills the other's
// dependency stalls (r5 post-mortem: 1240 cyc/step of exposed latency
// with a single chain). Raw s_barrier + lgkmcnt(0) only (no vmcnt drain).
__global__
__attribute__((amdgpu_flat_work_group_size(128, 128)))
__attribute__((amdgpu_waves_per_eu(1)))
void rnn_mfma(const float* __restrict__ x, const float* __restrict__ W,
              const float* __restrict__ U, const float* __restrict__ b,
              const float* __restrict__ Wd, const float* __restrict__ bd,
              float* __restrict__ out)
{
    __shared__ unsigned int hbuf[2][2][16][PITCH];   // [group][buf][row][col]
    __shared__ float headbuf[2][2][16];              // [group][wave][row]

    const int tid = threadIdx.x;
    const int w = tid >> 6;
    const int l = tid & 63;
    const int r = l & 15;
    const int g = l >> 4;
    const int rb = blockIdx.x * 32;

    const int c0 = 32 * w + r, c1 = c0 + 16;
    const bool cv0 = (c0 < HH), cv1 = (c1 < HH);
    short8 Whi0, Wlo0, Whi1, Wlo1;
    build_bfrag(W, 0, FF, c0, cv0, g, Whi0, Wlo0);
    build_bfrag(W, 0, FF, c1, cv1, g, Whi1, Wlo1);
    short8 Uhi00, Ulo00, Uhi01, Ulo01, Uhi10, Ulo10, Uhi11, Ulo11;
    build_bfrag(U, 0,  HH, c0, cv0, g, Uhi00, Ulo00);
    build_bfrag(U, 32, HH, c0, cv0, g, Uhi01, Ulo01);
    build_bfrag(U, 0,  HH, c1, cv1, g, Uhi10, Ulo10);
    build_bfrag(U, 32, HH, c1, cv1, g, Uhi11, Ulo11);
    const float bias0 = cv0 ? b[c0] : 0.0f;
    const float bias1 = cv1 ? b[c1] : 0.0f;
    const float wd0 = cv0 ? Wd[c0] : 0.0f;
    const float wd1 = cv1 ? Wd[c1] : 0.0f;

    const float* xrowA = x + ((size_t)(rb + r)) * TT * FF + 8 * g;
    const float* xrowB = xrowA + (size_t)16 * TT * FF;

    // xacc = bias + x_t @ W (3 split products per tile)
    auto do_nx = [&](float4 a, float4 bb, f32x4& n0, f32x4& n1) {
        short8 hi, lo;
        split8(a, bb, hi, lo);
        f32x4 t0 = {bias0, bias0, bias0, bias0};
        f32x4 t1 = {bias1, bias1, bias1, bias1};
        t0 = mfma16(hi, Whi0, t0); t0 = mfma16(lo, Whi0, t0); t0 = mfma16(hi, Wlo0, t0);
        t1 = mfma16(hi, Whi1, t1); t1 = mfma16(lo, Whi1, t1); t1 = mfma16(hi, Wlo1, t1);
        n0 = t0; n1 = t1;
    };

    // tot = xacc + h@U (two independent 3-chains per tile)
    auto h_chain = [&](uint32x4 p0a, uint32x4 p1a, uint32x4 p0b, uint32x4 p1b,
                       f32x4 xa0, f32x4 xa1, f32x4& tot0, f32x4& tot1) {
        short8 hh0, hl0, hh1, hl1;
        unpack8(p0a, p1a, hh0, hl0);
        unpack8(p0b, p1b, hh1, hl1);
        f32x4 ca = mfma16(hh0, Uhi00, xa0);
        f32x4 da = mfma16(hh0, Uhi10, xa1);
        f32x4 cb = {0.0f, 0.0f, 0.0f, 0.0f};
        f32x4 db = {0.0f, 0.0f, 0.0f, 0.0f};
        cb = mfma16(hh1, Uhi01, cb);
        db = mfma16(hh1, Uhi11, db);
        ca = mfma16(hl0, Uhi00, ca);
        da = mfma16(hl0, Uhi10, da);
        cb = mfma16(hl1, Uhi01, cb);
        db = mfma16(hl1, Uhi11, db);
        ca = mfma16(hh0, Ulo00, ca);
        da = mfma16(hh0, Ulo10, da);
        cb = mfma16(hh1, Ulo01, cb);
        db = mfma16(hh1, Ulo11, db);
        tot0 = ca + cb;
        tot1 = da + db;
    };

    auto finish = [&](f32x4 t0, f32x4 t1, float (&hf0)[4], float (&hf1)[4],
                      unsigned* wptr) {
#pragma unroll
        for (int i = 0; i < 4; ++i) {
            float h0 = fast_tanh(t0[i]);
            float h1 = fast_tanh(t1[i]);
            hf0[i] = h0; hf1[i] = h1;
            float r0 = h0 - trunc_hi(h0);
            float r1 = h1 - trunc_hi(h1);
            wptr[i * PITCH]      = __builtin_amdgcn_perm(__float_as_uint(r0), __float_as_uint(h0), 0x07060302u);
            wptr[i * PITCH + 16] = __builtin_amdgcn_perm(__float_as_uint(r1), __float_as_uint(h1), 0x07060302u);
        }
    };

    // prologue: xacc for t=0, prefetch x_1/x_2 pairs per group
    f32x4 xaccA0, xaccA1, xaccB0, xaccB1;
    do_nx(*(const float4*)(xrowA), *(const float4*)(xrowA + 4), xaccA0, xaccA1);
    do_nx(*(const float4*)(xrowB), *(const float4*)(xrowB + 4), xaccB0, xaccB1);
    float4 pA0a = *(const float4*)(xrowA + FF),     pA0b = *(const float4*)(xrowA + FF + 4);
    float4 pA1a = *(const float4*)(xrowA + 2 * FF), pA1b = *(const float4*)(xrowA + 2 * FF + 4);
    float4 pB0a = *(const float4*)(xrowB + FF),     pB0b = *(const float4*)(xrowB + FF + 4);
    float4 pB1a = *(const float4*)(xrowB + 2 * FF), pB1b = *(const float4*)(xrowB + 2 * FF + 4);

    float hfA0[4], hfA1[4], hfB0[4], hfB1[4];

    auto step = [&](int t, float4& qAa, float4& qAb, float4& qBa, float4& qBb) {
        const int buf = t & 1, nbuf = buf ^ 1;
        // h_t LDS reads for both groups issue first (deepest latency)
        uint32x4 pA0, pA1, pA2, pA3, pB0, pB1, pB2, pB3;
        if (t > 0) {
            const unsigned* a0 = &hbuf[0][buf][r][8 * g];
            const unsigned* a1 = &hbuf[0][buf][r][32 + 8 * g];
            pA0 = *(const uint32x4*)a0;  pA1 = *(const uint32x4*)(a0 + 4);
            pA2 = *(const uint32x4*)a1;  pA3 = *(const uint32x4*)(a1 + 4);
            const unsigned* b0 = &hbuf[1][buf][r][8 * g];
            const unsigned* b1 = &hbuf[1][buf][r][32 + 8 * g];
            pB0 = *(const uint32x4*)b0;  pB1 = *(const uint32x4*)(b0 + 4);
            pB2 = *(const uint32x4*)b1;  pB3 = *(const uint32x4*)(b1 + 4);
        }
        // x_{t+1}@W for both groups (independent of h)
        f32x4 nA0, nA1, nB0, nB1;
        do_nx(qAa, qAb, nA0, nA1);
        do_nx(qBa, qBb, nB0, nB1);
        int tn = t + 3; if (tn > TT - 1) tn = TT - 1;
        qAa = *(const float4*)(xrowA + (size_t)tn * FF);
        qAb = *(const float4*)(xrowA + (size_t)tn * FF + 4);
        qBa = *(const float4*)(xrowB + (size_t)tn * FF);
        qBb = *(const float4*)(xrowB + (size_t)tn * FF + 4);

        f32x4 tA0 = xaccA0, tA1 = xaccA1, tB0 = xaccB0, tB1 = xaccB1;
        if (t > 0) {
            h_chain(pA0, pA1, pA2, pA3, xaccA0, xaccA1, tA0, tA1);
            h_chain(pB0, pB1, pB2, pB3, xaccB0, xaccB1, tB0, tB1);
        }
        finish(tA0, tA1, hfA0, hfA1, &hbuf[0][nbuf][4 * g][32 * w + r]);
        finish(tB0, tB1, hfB0, hfB1, &hbuf[1][nbuf][4 * g][32 * w + r]);
        xaccA0 = nA0; xaccA1 = nA1; xaccB0 = nB0; xaccB1 = nB1;

        // LDS-only drain + raw barrier: x loads stay in flight (no vmcnt)
        __builtin_amdgcn_sched_barrier(0);
        asm volatile("s_waitcnt lgkmcnt(0)");
        __builtin_amdgcn_sched_barrier(0);
        __builtin_amdgcn_s_barrier();
        __builtin_amdgcn_sched_barrier(0);
    };

    for (int t = 0; t < TT; t += 2) {
        step(t,     pA0a, pA0b, pB0a, pB0b);
        step(t + 1, pA1a, pA1b, pB1a, pB1b);
    }

    // head: out[row] = relu(sum_j h[row][j]*Wd[j] + bd)
    auto head = [&](float (&hf0)[4], float (&hf1)[4], int grp) {
#pragma unroll
        for (int i = 0; i < 4; ++i) {
            float p = hf0[i] * wd0 + hf1[i] * wd1;
            p += __shfl_xor(p, 1);
            p += __shfl_xor(p, 2);
            p += __shfl_xor(p, 4);
            p += __shfl_xor(p, 8);
            if (r == 0) headbuf[grp][w][4 * g + i] = p;
        }
    };
    head(hfA0, hfA1, 0);
    head(hfB0, hfB1, 1);
    __syncthreads();
    if (w == 0 && l < 32) {
        const int grp = l >> 4, row = l & 15;
        out[rb + grp * 16 + row] =
            fmaxf(headbuf[grp][0][row] + headbuf[grp][1][row] + bd[0], 0.0f);
    }
}

extern "C" void kernel_launch(void* const* d_in, const int* in_sizes, int n_in,
                              void* d_out, int out_size, void* d_ws, size_t ws_size,
                              hipStream_t stream) {
    const float* x  = (const float*)d_in[0];
    const float* W  = (const float*)d_in[1];
    const float* U  = (const float*)d_in[2];
    const float* b  = (const float*)d_in[3];
    const float* Wd = (const float*)d_in[4];
    const float* bd = (const float*)d_in[5];
    float* out = (float*)d_out;
    const int B = out_size;                       // 4096
    dim3 grid(B / 32), block(128);                // 128 blocks, 2 waves, 32 rows
    hipLaunchKernelGGL(rnn_mfma, grid, block, 0, stream,
                       x, W, U, b, Wd, bd, out);
    (void)d_ws; (void)ws_size; (void)in_sizes; (void)n_in;
}

// Round 7
// 161.399 us; speedup vs baseline: 1.6068x; 1.6068x over previous
//
#include <hip/hip_runtime.h>

#define TT 200
#define FF 32
#define HH 50
#define PITCH 66   // f32 pitch: write banks exactly 2-way (free); reads measured next

typedef __attribute__((ext_vector_type(8))) short short8;   // 8 bf16 = 4 VGPR
typedef __attribute__((ext_vector_type(4))) float f32x4;

__device__ __forceinline__ unsigned short f2bf_rne(float f) {
    unsigned u = __float_as_uint(f);
    unsigned r = u + 0x7fffu + ((u >> 16) & 1u);
    return (unsigned short)(r >> 16);
}
// tanh(x) = 1 - 2/(e^{2x}+1): mul, exp, add, rcp, fma (2 trans + 3 VALU)
__device__ __forceinline__ float fast_tanh(float x) {
    float e = __expf(2.0f * x);
    return fmaf(-2.0f, __builtin_amdgcn_rcpf(e + 1.0f), 1.0f);
}
__device__ __forceinline__ f32x4 mfma16(short8 a, short8 b, f32x4 c) {
    return __builtin_amdgcn_mfma_f32_16x16x32_bf16(a, b, c, 0, 0, 0);
}

// Split fp32 column-slice of M[kdim x 50] into bf16 hi/lo B-frags.
// Layout (validated r4): lane(r,g) elem e -> B[k=kbase+8g+e][col=c].
__device__ __forceinline__ void build_bfrag(const float* __restrict__ M, int kbase,
                                            int kmax, int c, bool cv, int g,
                                            short8& hi, short8& lo) {
    typedef __attribute__((ext_vector_type(4))) unsigned int uint32x4;
    unsigned ph[4], pl[4];
#pragma unroll
    for (int p = 0; p < 4; ++p) {
        const int k0 = kbase + 8 * g + 2 * p, k1 = k0 + 1;
        float v0 = (cv && k0 < kmax) ? M[k0 * HH + c] : 0.0f;
        float v1 = (cv && k1 < kmax) ? M[k1 * HH + c] : 0.0f;
        unsigned short h0 = f2bf_rne(v0), h1 = f2bf_rne(v1);
        ph[p] = ((unsigned)h1 << 16) | h0;
        float r0 = v0 - __uint_as_float((unsigned)h0 << 16);
        float r1 = v1 - __uint_as_float((unsigned)h1 << 16);
        unsigned short l0 = f2bf_rne(r0), l1 = f2bf_rne(r1);
        pl[p] = ((unsigned)l1 << 16) | l0;
    }
    uint32x4 h4 = {ph[0], ph[1], ph[2], ph[3]};
    uint32x4 l4 = {pl[0], pl[1], pl[2], pl[3]};
    hi = __builtin_bit_cast(short8, h4);
    lo = __builtin_bit_cast(short8, l4);
}

// Truncation-split 8 fp32 -> bf16 hi/lo A-frags (hi=top16, lo=residual).
__device__ __forceinline__ void split8(float4 a, float4 b, short8& hi, short8& lo) {
    typedef __attribute__((ext_vector_type(4))) unsigned int uint32x4;
    float v[8] = {a.x, a.y, a.z, a.w, b.x, b.y, b.z, b.w};
    unsigned ph[4], pl[4];
#pragma unroll
    for (int p = 0; p < 4; ++p) {
        unsigned u0 = __float_as_uint(v[2 * p]);
        unsigned u1 = __float_as_uint(v[2 * p + 1]);
        ph[p] = __builtin_amdgcn_perm(u1, u0, 0x07060302u);
        float r0 = v[2 * p]     - __uint_as_float(u0 & 0xffff0000u);
        float r1 = v[2 * p + 1] - __uint_as_float(u1 & 0xffff0000u);
        pl[p] = __builtin_amdgcn_perm(__float_as_uint(r1), __float_as_uint(r0), 0x07060302u);
    }
    uint32x4 h4 = {ph[0], ph[1], ph[2], ph[3]};
    uint32x4 l4 = {pl[0], pl[1], pl[2], pl[3]};
    hi = __builtin_bit_cast(short8, h4);
    lo = __builtin_bit_cast(short8, l4);
}

// ONE WAVE owns 16 batch rows and ALL 50 hidden cols (4 N-tiles): the whole
// recurrence is wave-private. No s_barrier, no lgkmcnt drain: DS ops of one
// wave execute in order, and the h-write data-depends on the h-read through
// the MFMA chain; double-buffering covers compiler reordering. 36 MFMA/step
// (same total as the 2-wave split — r6 lesson: wall = 200 x step LATENCY,
// all rows already concurrent, so only the serial path length matters).
__global__
__attribute__((amdgpu_flat_work_group_size(64, 64)))
__attribute__((amdgpu_waves_per_eu(1, 1)))
void rnn_mfma(const float* __restrict__ x, const float* __restrict__ W,
              const float* __restrict__ U, const float* __restrict__ b,
              const float* __restrict__ Wd, const float* __restrict__ bd,
              float* __restrict__ out)
{
    __shared__ float hbuf[2][16][PITCH];   // h as raw f32; split on read side

    const int l = threadIdx.x & 63;
    const int r = l & 15;
    const int g = l >> 4;
    const int rb = blockIdx.x * 16;

    // Loop-invariant weight B-frags: W 8 + U 16 = 24 short8 = 96 VGPR.
    short8 Whi[4], Wlo[4], Uhi[4][2], Ulo[4][2];
    float bias[4], wd[4];
#pragma unroll
    for (int n = 0; n < 4; ++n) {
        const int c = 16 * n + r;
        const bool cv = (c < HH);
        build_bfrag(W, 0, FF, c, cv, g, Whi[n], Wlo[n]);
        build_bfrag(U, 0,  HH, c, cv, g, Uhi[n][0], Ulo[n][0]);
        build_bfrag(U, 32, HH, c, cv, g, Uhi[n][1], Ulo[n][1]);
        bias[n] = cv ? b[c] : 0.0f;
        wd[n]   = cv ? Wd[c] : 0.0f;
    }

    const float* xrow = x + (size_t)(rb + r) * TT * FF + 8 * g;

    f32x4 xacc[4];
    // nx[n] = bias + x_t @ W (3 split products per N-tile), off the h path
    auto do_nx = [&](float4 a, float4 b2, f32x4 (&nx)[4]) {
        short8 hi, lo;
        split8(a, b2, hi, lo);
#pragma unroll
        for (int n = 0; n < 4; ++n) {
            f32x4 t = {bias[n], bias[n], bias[n], bias[n]};
            t = mfma16(hi, Whi[n], t);
            t = mfma16(lo, Whi[n], t);
            t = mfma16(hi, Wlo[n], t);
            nx[n] = t;
        }
    };

    // prologue: xacc for t=0; prefetch x_1 (pa), x_2 (pb)
    do_nx(*(const float4*)(xrow), *(const float4*)(xrow + 4), xacc);
    float4 pa0 = *(const float4*)(xrow + FF),     pa1 = *(const float4*)(xrow + FF + 4);
    float4 pb0 = *(const float4*)(xrow + 2 * FF), pb1 = *(const float4*)(xrow + 2 * FF + 4);

    float hf[4][4];   // last h (C-layout), for the head

    auto step = [&](int t, bool first, float4& qa, float4& qb) {
        const int buf = t & 1, nbuf = buf ^ 1;
        // h_t reads issue first (longest latency on the path)
        float4 h0a, h0b, h1a, h1b;
        if (!first) {
            const float* base = &hbuf[buf][r][0];
            h0a = *(const float4*)(base + 8 * g);            // k 0..31 slice
            h0b = *(const float4*)(base + 8 * g + 4);
            h1a = *(const float4*)(base + 32 + 8 * g);       // k 32..49 slice
            h1b = *(const float4*)(base + 32 + 8 * g + 4);
        }
        // x_{t+1}@W (independent of h — fills the LDS-read latency)
        f32x4 nx[4];
        do_nx(qa, qb, nx);
        int tn = t + 3; if (tn > TT - 1) tn = TT - 1;
        qa = *(const float4*)(xrow + (size_t)tn * FF);
        qb = *(const float4*)(xrow + (size_t)tn * FF + 4);

        f32x4 tot[4];
        if (!first) {
            short8 hh0, hl0, hh1, hl1;
            split8(h0a, h0b, hh0, hl0);
            split8(h1a, h1b, hh1, hl1);
#pragma unroll
            for (int n = 0; n < 4; ++n) {   // 2 independent 3-chains per tile
                f32x4 ca = mfma16(hh0, Uhi[n][0], xacc[n]);
                f32x4 cb = {0.0f, 0.0f, 0.0f, 0.0f};
                cb = mfma16(hh1, Uhi[n][1], cb);
                ca = mfma16(hl0, Uhi[n][0], ca);
                cb = mfma16(hl1, Uhi[n][1], cb);
                ca = mfma16(hh0, Ulo[n][0], ca);
                cb = mfma16(hh1, Ulo[n][1], cb);
                tot[n] = ca + cb;
            }
        } else {
#pragma unroll
            for (int n = 0; n < 4; ++n) tot[n] = xacc[n];
        }

        // tanh + publish h_{t+1} (raw f32, wave-private, no sync)
        float* wbase = &hbuf[nbuf][0][0];
#pragma unroll
        for (int n = 0; n < 4; ++n) {
#pragma unroll
            for (int i = 0; i < 4; ++i) {
                float h = fast_tanh(tot[n][i]);
                hf[n][i] = h;
                wbase[(4 * g + i) * PITCH + 16 * n + r] = h;
            }
        }
#pragma unroll
        for (int n = 0; n < 4; ++n) xacc[n] = nx[n];
    };

    step(0, true, pa0, pa1);
    for (int t = 1; t < TT - 1; t += 2) {
        step(t,     false, pb0, pb1);
        step(t + 1, false, pa0, pa1);
    }
    step(TT - 1, false, pb0, pb1);

    // head: out[row] = relu(sum_c h[row][c]*Wd[c] + bd)
    const float bdv = bd[0];
#pragma unroll
    for (int i = 0; i < 4; ++i) {
        float p = hf[0][i] * wd[0] + hf[1][i] * wd[1]
                + hf[2][i] * wd[2] + hf[3][i] * wd[3];
        p += __shfl_xor(p, 1);
        p += __shfl_xor(p, 2);
        p += __shfl_xor(p, 4);
        p += __shfl_xor(p, 8);
        if (r == 0) out[rb + 4 * g + i] = fmaxf(p + bdv, 0.0f);
    }
}

extern "C" void kernel_launch(void* const* d_in, const int* in_sizes, int n_in,
                              void* d_out, int out_size, void* d_ws, size_t ws_size,
                              hipStream_t stream) {
    const float* x  = (const float*)d_in[0];
    const float* W  = (const float*)d_in[1];
    const float* U  = (const float*)d_in[2];
    const float* b  = (const float*)d_in[3];
    const float* Wd = (const float*)d_in[4];
    const float* bd = (const float*)d_in[5];
    float* out = (float*)d_out;
    const int B = out_size;                       // 4096
    dim3 grid(B / 16), block(64);                 // 256 blocks, 1 wave, 16 rows
    hipLaunchKernelGGL(rnn_mfma, grid, block, 0, stream,
                       x, W, U, b, Wd, bd, out);
    (void)d_ws; (void)ws_size; (void)in_sizes; (void)n_in;
}

// Round 8
// 107.484 us; speedup vs baseline: 2.4128x; 1.5016x over previous
//
#include <hip/hip_runtime.h>

#define TT 200
#define FF 32
#define HH 50
#define PITCH 68   // f32 pitch: 68%32=4 -> reads 2-way (free), writes spread

typedef __attribute__((ext_vector_type(8))) short short8;   // 8 bf16 = 4 VGPR
typedef __attribute__((ext_vector_type(4))) float f32x4;

__device__ __forceinline__ unsigned short f2bf_rne(float f) {
    unsigned u = __float_as_uint(f);
    unsigned r = u + 0x7fffu + ((u >> 16) & 1u);
    return (unsigned short)(r >> 16);
}
// tanh(x) = 1 - 2/(e^{2x}+1)
__device__ __forceinline__ float fast_tanh(float x) {
    float e = __expf(2.0f * x);
    return fmaf(-2.0f, __builtin_amdgcn_rcpf(e + 1.0f), 1.0f);
}
__device__ __forceinline__ f32x4 mfma16(short8 a, short8 b, f32x4 c) {
    return __builtin_amdgcn_mfma_f32_16x16x32_bf16(a, b, c, 0, 0, 0);
}

// Split fp32 column-slice of M[kdim x 50] into bf16 hi/lo B-frags.
// Layout (validated r4-r7): lane(r,g) elem e -> B[k=kbase+8g+e][col=c].
__device__ __forceinline__ void build_bfrag(const float* __restrict__ M, int kbase,
                                            int kmax, int c, bool cv, int g,
                                            short8& hi, short8& lo) {
    typedef __attribute__((ext_vector_type(4))) unsigned int uint32x4;
    unsigned ph[4], pl[4];
#pragma unroll
    for (int p = 0; p < 4; ++p) {
        const int k0 = kbase + 8 * g + 2 * p, k1 = k0 + 1;
        float v0 = (cv && k0 < kmax) ? M[k0 * HH + c] : 0.0f;
        float v1 = (cv && k1 < kmax) ? M[k1 * HH + c] : 0.0f;
        unsigned short h0 = f2bf_rne(v0), h1 = f2bf_rne(v1);
        ph[p] = ((unsigned)h1 << 16) | h0;
        float r0 = v0 - __uint_as_float((unsigned)h0 << 16);
        float r1 = v1 - __uint_as_float((unsigned)h1 << 16);
        unsigned short l0 = f2bf_rne(r0), l1 = f2bf_rne(r1);
        pl[p] = ((unsigned)l1 << 16) | l0;
    }
    uint32x4 h4 = {ph[0], ph[1], ph[2], ph[3]};
    uint32x4 l4 = {pl[0], pl[1], pl[2], pl[3]};
    hi = __builtin_bit_cast(short8, h4);
    lo = __builtin_bit_cast(short8, l4);
}

// Truncation-split 8 fp32 -> bf16 hi/lo A-frags (hi=top16, lo=residual).
__device__ __forceinline__ void split8(float4 a, float4 b, short8& hi, short8& lo) {
    typedef __attribute__((ext_vector_type(4))) unsigned int uint32x4;
    float v[8] = {a.x, a.y, a.z, a.w, b.x, b.y, b.z, b.w};
    unsigned ph[4], pl[4];
#pragma unroll
    for (int p = 0; p < 4; ++p) {
        unsigned u0 = __float_as_uint(v[2 * p]);
        unsigned u1 = __float_as_uint(v[2 * p + 1]);
        ph[p] = __builtin_amdgcn_perm(u1, u0, 0x07060302u);
        float r0 = v[2 * p]     - __uint_as_float(u0 & 0xffff0000u);
        float r1 = v[2 * p + 1] - __uint_as_float(u1 & 0xffff0000u);
        pl[p] = __builtin_amdgcn_perm(__float_as_uint(r1), __float_as_uint(r0), 0x07060302u);
    }
    uint32x4 h4 = {ph[0], ph[1], ph[2], ph[3]};
    uint32x4 l4 = {pl[0], pl[1], pl[2], pl[3]};
    hi = __builtin_bit_cast(short8, h4);
    lo = __builtin_bit_cast(short8, l4);
}

// 8 waves = 2 independent 16-row groups x 4 waves (one 16-col N-tile each).
// Grid 128 blocks -> 2 waves/SIMD: group A's stalls (LDS round trip, MFMA
// chains, barrier wait) are filled by group B's issue on the same SIMD —
// the r6 interleaving idea done by hardware TLP instead of the compiler.
// Per wave per step: 4 ds_read_b128, 3 splits, 9 MFMA, 4 tanh, 4 ds_write,
// raw s_barrier + lgkmcnt(0) drain only (x prefetch stays in flight).
__global__
__attribute__((amdgpu_flat_work_group_size(512, 512)))
__attribute__((amdgpu_waves_per_eu(2)))
void rnn_mfma(const float* __restrict__ x, const float* __restrict__ W,
              const float* __restrict__ U, const float* __restrict__ b,
              const float* __restrict__ Wd, const float* __restrict__ bd,
              float* __restrict__ out)
{
    __shared__ float hbuf[2][2][16][PITCH];   // [grp][buf][row][col]
    __shared__ float headbuf[2][4][16];       // [grp][tile][row]

    const int tid = threadIdx.x;
    const int w   = tid >> 6;
    const int grp = w >> 2;        // row group 0/1
    const int n   = w & 3;         // N-tile 0..3 (cols 16n..16n+15)
    const int l   = tid & 63;
    const int r   = l & 15;
    const int g   = l >> 4;
    const int rb  = blockIdx.x * 32 + grp * 16;

    // Loop-invariant weight frags for this wave's 16 cols: 6 short8 = 24 VGPR
    const int c = 16 * n + r;
    const bool cv = (c < HH);
    short8 Whi, Wlo, Uhi0, Ulo0, Uhi1, Ulo1;
    build_bfrag(W, 0, FF, c, cv, g, Whi, Wlo);
    build_bfrag(U, 0,  HH, c, cv, g, Uhi0, Ulo0);
    build_bfrag(U, 32, HH, c, cv, g, Uhi1, Ulo1);
    const float bias = cv ? b[c] : 0.0f;
    const float wd   = cv ? Wd[c] : 0.0f;

    const float* xrow = x + (size_t)(rb + r) * TT * FF + 8 * g;

    // nx = bias + x_t @ W (3 split products, 1 tile) — off the h path
    auto do_nx = [&](float4 a, float4 b2) -> f32x4 {
        short8 hi, lo;
        split8(a, b2, hi, lo);
        f32x4 t = {bias, bias, bias, bias};
        t = mfma16(hi, Whi, t);
        t = mfma16(lo, Whi, t);
        t = mfma16(hi, Wlo, t);
        return t;
    };

    // prologue: xacc for t=0; prefetch x_1 (pa), x_2 (pb)
    f32x4 xacc = do_nx(*(const float4*)(xrow), *(const float4*)(xrow + 4));
    float4 pa0 = *(const float4*)(xrow + FF),     pa1 = *(const float4*)(xrow + FF + 4);
    float4 pb0 = *(const float4*)(xrow + 2 * FF), pb1 = *(const float4*)(xrow + 2 * FF + 4);

    float hf[4];   // final h (C-layout) for the head

    auto step = [&](int t, bool first, float4& qa, float4& qb) {
        const int buf = t & 1, nbuf = buf ^ 1;
        // h_t reads first (deepest latency on the path)
        float4 h0a, h0b, h1a, h1b;
        if (!first) {
            const float* base = &hbuf[grp][buf][r][0];
            h0a = *(const float4*)(base + 8 * g);        // k 0..31 slice
            h0b = *(const float4*)(base + 8 * g + 4);
            h1a = *(const float4*)(base + 32 + 8 * g);   // k 32..49 slice
            h1b = *(const float4*)(base + 32 + 8 * g + 4);
        }
        // x_{t+1}@W (independent of h)
        f32x4 nx = do_nx(qa, qb);
        int tn = t + 3; if (tn > TT - 1) tn = TT - 1;
        qa = *(const float4*)(xrow + (size_t)tn * FF);
        qb = *(const float4*)(xrow + (size_t)tn * FF + 4);

        f32x4 tot = xacc;
        if (!first) {
            short8 hh0, hl0, hh1, hl1;
            split8(h0a, h0b, hh0, hl0);
            split8(h1a, h1b, hh1, hl1);
            // two independent 3-chains, xacc as C-in of chain a
            f32x4 ca = mfma16(hh0, Uhi0, xacc);
            f32x4 cb = {0.0f, 0.0f, 0.0f, 0.0f};
            cb = mfma16(hh1, Uhi1, cb);
            ca = mfma16(hl0, Uhi0, ca);
            cb = mfma16(hl1, Uhi1, cb);
            ca = mfma16(hh0, Ulo0, ca);
            cb = mfma16(hh1, Ulo1, cb);
            tot = ca + cb;
        }

        // tanh + publish h_{t+1} for this wave's 16 cols
        float* wbase = &hbuf[grp][nbuf][0][0];
#pragma unroll
        for (int i = 0; i < 4; ++i) {
            float h = fast_tanh(tot[i]);
            hf[i] = h;
            wbase[(4 * g + i) * PITCH + 16 * n + r] = h;
        }
        xacc = nx;

        // LDS-only drain + raw barrier (no vmcnt: x loads stay in flight)
        __builtin_amdgcn_sched_barrier(0);
        asm volatile("s_waitcnt lgkmcnt(0)");
        __builtin_amdgcn_sched_barrier(0);
        __builtin_amdgcn_s_barrier();
        __builtin_amdgcn_sched_barrier(0);
    };

    step(0, true, pa0, pa1);
    for (int t = 1; t < TT - 1; t += 2) {
        step(t,     false, pb0, pb1);
        step(t + 1, false, pa0, pa1);
    }
    step(TT - 1, false, pb0, pb1);

    // head: partial per tile, then combine across the 4 tiles
#pragma unroll
    for (int i = 0; i < 4; ++i) {
        float p = hf[i] * wd;
        p += __shfl_xor(p, 1);
        p += __shfl_xor(p, 2);
        p += __shfl_xor(p, 4);
        p += __shfl_xor(p, 8);
        if (r == 0) headbuf[grp][n][4 * g + i] = p;
    }
    __syncthreads();
    if (tid < 32) {
        const int g2 = tid >> 4, row = tid & 15;
        out[blockIdx.x * 32 + g2 * 16 + row] =
            fmaxf(headbuf[g2][0][row] + headbuf[g2][1][row] +
                  headbuf[g2][2][row] + headbuf[g2][3][row] + bd[0], 0.0f);
    }
}

extern "C" void kernel_launch(void* const* d_in, const int* in_sizes, int n_in,
                              void* d_out, int out_size, void* d_ws, size_t ws_size,
                              hipStream_t stream) {
    const float* x  = (const float*)d_in[0];
    const float* W  = (const float*)d_in[1];
    const float* U  = (const float*)d_in[2];
    const float* b  = (const float*)d_in[3];
    const float* Wd = (const float*)d_in[4];
    const float* bd = (const float*)d_in[5];
    float* out = (float*)d_out;
    const int B = out_size;                       // 4096
    dim3 grid(B / 32), block(512);                // 128 blocks, 8 waves, 32 rows
    hipLaunchKernelGGL(rnn_mfma, grid, block, 0, stream,
                       x, W, U, b, Wd, bd, out);
    (void)d_ws; (void)ws_size; (void)in_sizes; (void)n_in;
}